// Round 3
// baseline (594.239 us; speedup 1.0000x reference)
//
#include <hip/hip_runtime.h>
#include <stdint.h>

// Problem constants (fixed by setup_inputs; all tensors f32)
#define B_ROWS 4096
#define D_IN   784
#define H_DIM  800
#define D_OUT  10
#define T_SIM  32
#define N_ELEM (B_ROWS * D_IN)   // 3211264
#define CAP    448               // spiking-list cap/row (mean ~376, sd ~14)

// ---------------------------------------------------------------------------
// Bit-exact JAX threefry2x32 (key = PRNGKey(42) = {0, 42})
// ---------------------------------------------------------------------------
__device__ __forceinline__ void threefry2x32(uint32_t k0, uint32_t k1,
                                             uint32_t& x0, uint32_t& x1) {
  uint32_t ks0 = k0, ks1 = k1, ks2 = k0 ^ k1 ^ 0x1BD11BDAu;
  x0 += ks0; x1 += ks1;
#define TF_RND(r) { x0 += x1; x1 = (x1 << (r)) | (x1 >> (32 - (r))); x1 ^= x0; }
  TF_RND(13) TF_RND(15) TF_RND(26) TF_RND(6)
  x0 += ks1; x1 += ks2 + 1u;
  TF_RND(17) TF_RND(29) TF_RND(16) TF_RND(24)
  x0 += ks2; x1 += ks0 + 2u;
  TF_RND(13) TF_RND(15) TF_RND(26) TF_RND(6)
  x0 += ks0; x1 += ks1 + 3u;
  TF_RND(17) TF_RND(29) TF_RND(16) TF_RND(24)
  x0 += ks1; x1 += ks2 + 4u;
  TF_RND(13) TF_RND(15) TF_RND(26) TF_RND(6)
  x0 += ks2; x1 += ks0 + 5u;
#undef TF_RND
}

// K0 (R13 verbatim): x_fixed[i] = (u[i] < x[i]) ? 1 : 0.
__global__ __launch_bounds__(256) void gen_xfixed(const float* __restrict__ x,
                                                  float* __restrict__ xf) {
  int i = blockIdx.x * blockDim.x + threadIdx.x;
  if (i >= N_ELEM) return;
  uint32_t c0 = 0u, c1 = (uint32_t)i;
  threefry2x32(0u, 42u, c0, c1);
  uint32_t bits = c0 ^ c1;
  float u = __uint_as_float((bits >> 9) | 0x3F800000u) - 1.0f;
  xf[i] = (u < x[i]) ? 1.0f : 0.0f;
}

// ---------------------------------------------------------------------------
// K1 (R3): global-direct GEMM + mask epilogue.  ZERO LDS, ZERO barriers.
// R2 evidence: LDS-staged version was latency/issue-bound (VALUBusy 40%,
// <50% of VALU issue was fma; 98 barrier-drains/block).  Here each wave
// streams A(xf) and B(W1) straight from global: L1 gets 4x line reuse
// (64B = 4 k4-steps), W1 is L2-resident.  Thread tile 8m x 4h -> 1.5 B/fma
// operand traffic.  1 wave/block, 1600 blocks, no bounds checks needed
// (4096 = 64*64, 800 = 25*32).
// Exactness: per output, single f32 acc, strict ascending-k fma chain
// (identical sequence to the R2/R13 passing kernels); epilogue identical.
// ---------------------------------------------------------------------------
__global__ __launch_bounds__(64, 3) void gemm_masks(const float* __restrict__ xf,
                                                    const float* __restrict__ W1,
                                                    const float* __restrict__ b1,
                                                    uint32_t* __restrict__ mb) {
  const int lane = threadIdx.x;          // 0..63
  const int mq = lane >> 3;              // 0..7
  const int hq = lane & 7;               // 0..7
  const int m0 = blockIdx.y * 64 + mq * 8;   // 8 consecutive m-rows
  const int h0 = blockIdx.x * 32 + hq * 4;   // 4 consecutive h-rows

  const float* pa[8];
  const float* pw[4];
#pragma unroll
  for (int i = 0; i < 8; i++) pa[i] = xf + (size_t)(m0 + i) * D_IN;
#pragma unroll
  for (int j = 0; j < 4; j++) pw[j] = W1 + (size_t)(h0 + j) * D_IN;

  float acc[8][4] = {};

  float4 A0[8], B0[4], A1[8], B1[4];

#define LOADS(Ab, Bb, kofs)                                         \
  {                                                                 \
    _Pragma("unroll")                                               \
    for (int i = 0; i < 8; i++)                                     \
      Ab[i] = *(const float4*)(pa[i] + (kofs));                     \
    _Pragma("unroll")                                               \
    for (int j = 0; j < 4; j++)                                     \
      Bb[j] = *(const float4*)(pw[j] + (kofs));                     \
  }

  // kk-ascending per accumulator: kk outer, mi/hi inner (independent accs)
#define FMA4(Ab, Bb)                                                \
  {                                                                 \
    float a[8], b[4];                                               \
    _Pragma("unroll")                                               \
    for (int kk = 0; kk < 4; kk++) {                                \
      a[0] = ((kk==0)?Ab[0].x:(kk==1)?Ab[0].y:(kk==2)?Ab[0].z:Ab[0].w); \
      a[1] = ((kk==0)?Ab[1].x:(kk==1)?Ab[1].y:(kk==2)?Ab[1].z:Ab[1].w); \
      a[2] = ((kk==0)?Ab[2].x:(kk==1)?Ab[2].y:(kk==2)?Ab[2].z:Ab[2].w); \
      a[3] = ((kk==0)?Ab[3].x:(kk==1)?Ab[3].y:(kk==2)?Ab[3].z:Ab[3].w); \
      a[4] = ((kk==0)?Ab[4].x:(kk==1)?Ab[4].y:(kk==2)?Ab[4].z:Ab[4].w); \
      a[5] = ((kk==0)?Ab[5].x:(kk==1)?Ab[5].y:(kk==2)?Ab[5].z:Ab[5].w); \
      a[6] = ((kk==0)?Ab[6].x:(kk==1)?Ab[6].y:(kk==2)?Ab[6].z:Ab[6].w); \
      a[7] = ((kk==0)?Ab[7].x:(kk==1)?Ab[7].y:(kk==2)?Ab[7].z:Ab[7].w); \
      b[0] = ((kk==0)?Bb[0].x:(kk==1)?Bb[0].y:(kk==2)?Bb[0].z:Bb[0].w); \
      b[1] = ((kk==0)?Bb[1].x:(kk==1)?Bb[1].y:(kk==2)?Bb[1].z:Bb[1].w); \
      b[2] = ((kk==0)?Bb[2].x:(kk==1)?Bb[2].y:(kk==2)?Bb[2].z:Bb[2].w); \
      b[3] = ((kk==0)?Bb[3].x:(kk==1)?Bb[3].y:(kk==2)?Bb[3].z:Bb[3].w); \
      _Pragma("unroll")                                             \
      for (int mi = 0; mi < 8; mi++)                                \
        _Pragma("unroll")                                           \
        for (int hi = 0; hi < 4; hi++)                              \
          acc[mi][hi] = __builtin_fmaf(a[mi], b[hi], acc[mi][hi]);  \
    }                                                               \
  }

  LOADS(A0, B0, 0);
#pragma unroll 1
  for (int k = 0; k < D_IN; k += 8) {    // 784 = 98*8
    LOADS(A1, B1, k + 4);                // prefetch second half (always < 784)
    FMA4(A0, B0);                        // k .. k+3
    if (k + 8 < D_IN) LOADS(A0, B0, k + 8);
    FMA4(A1, B1);                        // k+4 .. k+7
  }
#undef LOADS
#undef FMA4

  // Epilogue: + b1 (f32 add like ref), exact f32 IF-period loop, emit mask32
  float4 bb = *(const float4*)&b1[h0];
#pragma unroll
  for (int mi = 0; mi < 8; mi++) {
    int m = m0 + mi;
    float c4[4] = {acc[mi][0] + bb.x, acc[mi][1] + bb.y,
                   acc[mi][2] + bb.z, acc[mi][3] + bb.w};
    uint32_t mk4[4];
#pragma unroll
    for (int ni = 0; ni < 4; ni++) {
      float c = c4[ni];
      float v = 0.0f;
      int p = 0;
#pragma unroll 1
      for (int s = 1; s <= T_SIM; s++) {
        float h1 = v + c;                 // f32 add, as reference
        if (h1 >= 1.0f) { p = s; break; }
        v = h1;
      }
      uint32_t mk = 0;
      if (p) for (int s = p; s <= T_SIM; s += p) mk |= 1u << (s - 1);
      mk4[ni] = mk;
    }
    *(uint4*)&mb[(size_t)m * H_DIM + h0] =
        make_uint4(mk4[0], mk4[1], mk4[2], mk4[3]);
  }
}

// ---------------------------------------------------------------------------
// K2: SNN scan — proven 40 KB / 4-blocks-per-CU version (unchanged from R2,
// ~130 us).  LDS = W2T 32000 + pkS 7168 (+small) < 40960 -> 4 blocks/CU.
// Exec per entry: 1 b64 pk read + 1 b64 w read (both <=2-distinct,
// conflict-free) + ~4 VALU.
// Exactness: per (row,t,o) ascending-h single-accumulator gated fold —
// never-spiking h skipped (+0 identity), each step +w or +0 (select form;
// pads have mask=0). Overflow (>CAP) -> gated full scan, same order.
// ---------------------------------------------------------------------------
__global__ __launch_bounds__(320) void snn_scan(const uint32_t* __restrict__ mb,
                                                const float* __restrict__ W2,
                                                const float* __restrict__ b2,
                                                float* __restrict__ out) {
  __shared__ __align__(16) float W2T[H_DIM * D_OUT];  // [h][o], 32000 B
  __shared__ __align__(16) uint2 pkS[2][CAP];         // {h*40, mask}, 7168 B
  __shared__ int   lenS[2];
  __shared__ float b2f[D_OUT];
  float* c2s = (float*)&pkS[0][0];            // union: [r][t][o], 2560 B
  const int tid  = threadIdx.x;               // 0..319
  const int row0 = blockIdx.x * 2;

  if (tid < D_OUT) b2f[tid] = b2[tid];

  if (tid < 128) {
    // ---- Build (waves 0-1): ballot-compact mask words, ascending h ----
    const int r = tid >> 6, ln = tid & 63;
    const uint64_t lm = (1ull << ln) - 1ull;
    const uint32_t* mrow = mb + (size_t)(row0 + r) * H_DIM;
    uint32_t mv[13];
#pragma unroll
    for (int ch = 0; ch < 13; ++ch) {         // independent coalesced loads
      int h = ch * 64 + ln;
      mv[ch] = (h < H_DIM) ? mrow[h] : 0u;
    }
    int off = 0;
#pragma unroll
    for (int ch = 0; ch < 13; ++ch) {
      bool g = (mv[ch] != 0u);
      uint64_t bal = __ballot(g);
      int pos = off + __popcll(bal & lm);
      if (g && pos < CAP) {
        uint2 pk; pk.x = (uint32_t)((ch * 64 + ln) * 40); pk.y = mv[ch];
        pkS[r][pos] = pk;
      }
      off += __popcll(bal);
    }
    if (off <= CAP) {                         // self-pad to multiple of 64
      int lp = (off + 63) & ~63;              // <= CAP since off <= CAP
      int i = off + ln;
      if (i < lp) { pkS[r][i].x = 0u; pkS[r][i].y = 0u; }
    }
    if (ln == 0) lenS[r] = off;
  } else {
    // ---- W2T staging (waves 2-4): coalesced read, LDS scatter ----
    for (int e = tid - 128; e < H_DIM * D_OUT; e += 192) {
      int o = e / H_DIM, h = e - o * H_DIM;
      W2T[h * D_OUT + o] = W2[e];
    }
  }
  __syncthreads();

  // ---- Exec: wave j = o-pair, lanes (t, r); 2 LDS ops per entry ----
  float s0 = 0.0f, s1 = 0.0f;
  const int j = tid >> 6;                     // 0..4
  const int lane = tid & 63;
  const int t = lane & 31;
  const int r = lane >> 5;
  const bool ovf = (lenS[0] > CAP) || (lenS[1] > CAP);
  {
    if (!ovf) {
      const int Lpad = (lenS[r] + 63) & ~63;  // per-r trip count (divergent ok)
      const uint2* pp = pkS[r];
      const char* wbase = (const char*)W2T + 8 * j;
#pragma unroll 4
      for (int i = 0; i < Lpad; ++i) {
        uint2 pk = pp[i];                     // b64, 2-distinct broadcast
        float2 w = *(const float2*)(wbase + pk.x);  // b64, 2-distinct
        bool g = (pk.y >> t) & 1u;
        s0 += g ? w.x : 0.0f;                 // identical op to ref (+w / +0)
        s1 += g ? w.y : 0.0f;
      }
    } else {                                  // overflow fallback: gated scan
      const uint32_t* mrow = mb + (size_t)(row0 + r) * H_DIM;
      const uint32_t vbit = 1u << t;
      for (int h = 0; h < H_DIM; ++h) {
        uint32_t mk = mrow[h];
        float2 w = *(const float2*)&W2T[h * D_OUT + 2 * j];
        s0 += (mk & vbit) ? w.x : 0.0f;
        s1 += (mk & vbit) ? w.y : 0.0f;
      }
    }
  }
  __syncthreads();                            // all pk reads complete
  c2s[((r * T_SIM) + t) * D_OUT + 2 * j]     = s0;   // union region write
  c2s[((r * T_SIM) + t) * D_OUT + 2 * j + 1] = s1;
  __syncthreads();

  // ---- Layer-2 IF scan + spike count (exact f32 ref order) ----
  if (tid < 2 * D_OUT) {
    const int rr = tid / D_OUT, o = tid % D_OUT;
    const float bb = b2f[o];
    float v = 0.0f; int cnt = 0;
#pragma unroll
    for (int tt = 0; tt < T_SIM; ++tt) {
      float cur2 = c2s[((rr * T_SIM) + tt) * D_OUT + o] + bb;  // f32 add
      float h2 = v + cur2;                    // f32 add
      bool spk = (h2 >= 1.0f);
      cnt += spk ? 1 : 0;
      v = spk ? 0.0f : h2;
    }
    out[(size_t)(row0 + rr) * D_OUT + o] = (float)cnt;
  }
}

// ---------------------------------------------------------------------------
extern "C" void kernel_launch(void* const* d_in, const int* in_sizes, int n_in,
                              void* d_out, int out_size, void* d_ws, size_t ws_size,
                              hipStream_t stream) {
  const float* x  = (const float*)d_in[0];
  const float* W1 = (const float*)d_in[1];
  const float* b1 = (const float*)d_in[2];
  const float* W2 = (const float*)d_in[3];
  const float* b2 = (const float*)d_in[4];
  float* outp = (float*)d_out;

  float*    xf = (float*)d_ws;                      // N_ELEM f32 (12.85 MB)
  uint32_t* mbuf = (uint32_t*)(xf + N_ELEM);        // B*H u32   (13.1 MB)

  gen_xfixed<<<N_ELEM / 256, 256, 0, stream>>>(x, xf);

  dim3 g1(H_DIM / 32, B_ROWS / 64);                 // 25 x 64 = 1600 blocks
  gemm_masks<<<g1, 64, 0, stream>>>(xf, W1, b1, mbuf);

  snn_scan<<<B_ROWS / 2, 320, 0, stream>>>(mbuf, W2, b2, outp);
}

// Round 4
// 304.412 us; speedup vs baseline: 1.9521x; 1.9521x over previous
//
#include <hip/hip_runtime.h>
#include <stdint.h>

// Problem constants (fixed by setup_inputs; all tensors f32)
#define B_ROWS 4096
#define D_IN   784
#define H_DIM  800
#define D_OUT  10
#define T_SIM  32
#define N_ELEM (B_ROWS * D_IN)   // 3211264
#define CAP    448               // spiking-list cap/row (mean ~376, sd ~14)

// ---------------------------------------------------------------------------
// Bit-exact JAX threefry2x32 (key = PRNGKey(42) = {0, 42})
// ---------------------------------------------------------------------------
__device__ __forceinline__ void threefry2x32(uint32_t k0, uint32_t k1,
                                             uint32_t& x0, uint32_t& x1) {
  uint32_t ks0 = k0, ks1 = k1, ks2 = k0 ^ k1 ^ 0x1BD11BDAu;
  x0 += ks0; x1 += ks1;
#define TF_RND(r) { x0 += x1; x1 = (x1 << (r)) | (x1 >> (32 - (r))); x1 ^= x0; }
  TF_RND(13) TF_RND(15) TF_RND(26) TF_RND(6)
  x0 += ks1; x1 += ks2 + 1u;
  TF_RND(17) TF_RND(29) TF_RND(16) TF_RND(24)
  x0 += ks2; x1 += ks0 + 2u;
  TF_RND(13) TF_RND(15) TF_RND(26) TF_RND(6)
  x0 += ks0; x1 += ks1 + 3u;
  TF_RND(17) TF_RND(29) TF_RND(16) TF_RND(24)
  x0 += ks1; x1 += ks2 + 4u;
  TF_RND(13) TF_RND(15) TF_RND(26) TF_RND(6)
  x0 += ks2; x1 += ks0 + 5u;
#undef TF_RND
}

// K0 (R13 verbatim): x_fixed[i] = (u[i] < x[i]) ? 1 : 0.
__global__ __launch_bounds__(256) void gen_xfixed(const float* __restrict__ x,
                                                  float* __restrict__ xf) {
  int i = blockIdx.x * blockDim.x + threadIdx.x;
  if (i >= N_ELEM) return;
  uint32_t c0 = 0u, c1 = (uint32_t)i;
  threefry2x32(0u, 42u, c0, c1);
  uint32_t bits = c0 ^ c1;
  float u = __uint_as_float((bits >> 9) | 0x3F800000u) - 1.0f;
  xf[i] = (u < x[i]) ? 1.0f : 0.0f;
}

// ---------------------------------------------------------------------------
// K1 (R4): R13's proven 64x64 / 4x4 structure (131 us measured), with ONE
// change: double-buffered LDS tiles -> a single __syncthreads per K-tile
// (49 barrier drains instead of 98).  R3's global-direct variant spilled
// (VGPR 84 << tile needs, WRITE_SIZE 195 MB scratch) — reverted.
// Race-safety of single barrier: iter t reads buf[t&1], writes buf[(t+1)&1];
// the end-of-iter sync separates iter t's reads from iter t+1's writes to
// the same buffer.  Arithmetic chain identical to R13: per output a single
// f32 accumulator, strict ascending-k fma; epilogue identical.
// LDS 17.4 KB, ~56 VGPR; grid 832 blocks (3.25/CU, ~13 waves/CU).
// ---------------------------------------------------------------------------
#define BM 64
#define BN 64
#define BK 16

__global__ __launch_bounds__(256) void gemm_masks(const float* __restrict__ xf,
                                                  const float* __restrict__ W1,
                                                  const float* __restrict__ b1,
                                                  uint32_t* __restrict__ mb) {
  __shared__ __align__(16) float As[2][BK][BM + 4];   // 2 x 4352 B
  __shared__ __align__(16) float Bs[2][BK][BN + 4];   // 2 x 4352 B
  const int m0 = blockIdx.y * BM;
  const int n0 = blockIdx.x * BN;
  const int t  = threadIdx.x;        // 0..255
  const int tx = t & 15, ty = t >> 4;
  const int sM = t >> 2;             // 0..63 staging row
  const int sK = (t & 3) * 4;        // 0,4,8,12
  const int hB = n0 + sM;
  const bool bOK = (hB < H_DIM);
  const float* aptr = xf + (size_t)(m0 + sM) * D_IN + sK;
  const float* bptr = W1 + (size_t)(bOK ? hB : 0) * D_IN + sK;

  float4 a4 = *(const float4*)(aptr);
  float4 b4 = *(const float4*)(bptr);
  if (!bOK) { b4.x = b4.y = b4.z = b4.w = 0.0f; }

  // stage tile 0 into buffer 0
  As[0][sK + 0][sM] = a4.x; As[0][sK + 1][sM] = a4.y;
  As[0][sK + 2][sM] = a4.z; As[0][sK + 3][sM] = a4.w;
  Bs[0][sK + 0][sM] = b4.x; Bs[0][sK + 1][sM] = b4.y;
  Bs[0][sK + 2][sM] = b4.z; Bs[0][sK + 3][sM] = b4.w;
  __syncthreads();

  float acc[4][4] = {};
  const int NT = D_IN / BK;                 // 49 tiles, ascending k
#pragma unroll 1
  for (int tt = 0; tt < NT; ++tt) {
    const int cur = tt & 1;
    const bool more = (tt + 1 < NT);
    if (more) {                             // global prefetch for tile tt+1
      a4 = *(const float4*)(aptr + (tt + 1) * BK);
      b4 = *(const float4*)(bptr + (tt + 1) * BK);
      if (!bOK) { b4.x = b4.y = b4.z = b4.w = 0.0f; }
    }
    const float (*Ac)[BM + 4] = As[cur];
    const float (*Bc)[BN + 4] = Bs[cur];
#pragma unroll
    for (int kk = 0; kk < BK; kk++) {       // strict ascending k, single acc
      float4 av = *(const float4*)&Ac[kk][ty * 4];   // ds_read_b128
      float4 bv = *(const float4*)&Bc[kk][tx * 4];   // ds_read_b128
      float a[4] = {av.x, av.y, av.z, av.w};
      float b[4] = {bv.x, bv.y, bv.z, bv.w};
#pragma unroll
      for (int mi = 0; mi < 4; mi++)
#pragma unroll
        for (int ni = 0; ni < 4; ni++)
          acc[mi][ni] = __builtin_fmaf(a[mi], b[ni], acc[mi][ni]);
    }
    if (more) {                             // stage tile tt+1 into other buf
      const int nxt = cur ^ 1;
      As[nxt][sK + 0][sM] = a4.x; As[nxt][sK + 1][sM] = a4.y;
      As[nxt][sK + 2][sM] = a4.z; As[nxt][sK + 3][sM] = a4.w;
      Bs[nxt][sK + 0][sM] = b4.x; Bs[nxt][sK + 1][sM] = b4.y;
      Bs[nxt][sK + 2][sM] = b4.z; Bs[nxt][sK + 3][sM] = b4.w;
      __syncthreads();                      // ONE barrier per K-tile
    }
  }

  // Epilogue: + b1 (f32 add like ref), exact f32 IF-period loop, emit mask32
  const int hOut = n0 + tx * 4;              // multiple of 4
  if (hOut < H_DIM) {
    float4 bb = *(const float4*)&b1[hOut];
#pragma unroll
    for (int mi = 0; mi < 4; mi++) {
      int m = m0 + ty * 4 + mi;
      float c4[4] = {acc[mi][0] + bb.x, acc[mi][1] + bb.y,
                     acc[mi][2] + bb.z, acc[mi][3] + bb.w};
      uint32_t mk4[4];
#pragma unroll
      for (int ni = 0; ni < 4; ni++) {
        float c = c4[ni];
        float v = 0.0f;
        int p = 0;
#pragma unroll 1
        for (int s = 1; s <= T_SIM; s++) {
          float h1 = v + c;                   // f32 add, as reference
          if (h1 >= 1.0f) { p = s; break; }
          v = h1;
        }
        uint32_t mk = 0;
        if (p) for (int s = p; s <= T_SIM; s += p) mk |= 1u << (s - 1);
        mk4[ni] = mk;
      }
      *(uint4*)&mb[(size_t)m * H_DIM + hOut] =
          make_uint4(mk4[0], mk4[1], mk4[2], mk4[3]);
    }
  }
}

// ---------------------------------------------------------------------------
// K2: SNN scan — proven 40 KB / 4-blocks-per-CU version (unchanged, ~130 us).
// LDS = W2T 32000 + pkS 7168 (+small) < 40960 -> 4 blocks/CU.
// Exec per entry: 1 b64 pk read + 1 b64 w read (both <=2-distinct,
// conflict-free) + ~4 VALU.
// Exactness: per (row,t,o) ascending-h single-accumulator gated fold —
// never-spiking h skipped (+0 identity), each step +w or +0 (select form;
// pads have mask=0). Overflow (>CAP) -> gated full scan, same order.
// ---------------------------------------------------------------------------
__global__ __launch_bounds__(320) void snn_scan(const uint32_t* __restrict__ mb,
                                                const float* __restrict__ W2,
                                                const float* __restrict__ b2,
                                                float* __restrict__ out) {
  __shared__ __align__(16) float W2T[H_DIM * D_OUT];  // [h][o], 32000 B
  __shared__ __align__(16) uint2 pkS[2][CAP];         // {h*40, mask}, 7168 B
  __shared__ int   lenS[2];
  __shared__ float b2f[D_OUT];
  float* c2s = (float*)&pkS[0][0];            // union: [r][t][o], 2560 B
  const int tid  = threadIdx.x;               // 0..319
  const int row0 = blockIdx.x * 2;

  if (tid < D_OUT) b2f[tid] = b2[tid];

  if (tid < 128) {
    // ---- Build (waves 0-1): ballot-compact mask words, ascending h ----
    const int r = tid >> 6, ln = tid & 63;
    const uint64_t lm = (1ull << ln) - 1ull;
    const uint32_t* mrow = mb + (size_t)(row0 + r) * H_DIM;
    uint32_t mv[13];
#pragma unroll
    for (int ch = 0; ch < 13; ++ch) {         // independent coalesced loads
      int h = ch * 64 + ln;
      mv[ch] = (h < H_DIM) ? mrow[h] : 0u;
    }
    int off = 0;
#pragma unroll
    for (int ch = 0; ch < 13; ++ch) {
      bool g = (mv[ch] != 0u);
      uint64_t bal = __ballot(g);
      int pos = off + __popcll(bal & lm);
      if (g && pos < CAP) {
        uint2 pk; pk.x = (uint32_t)((ch * 64 + ln) * 40); pk.y = mv[ch];
        pkS[r][pos] = pk;
      }
      off += __popcll(bal);
    }
    if (off <= CAP) {                         // self-pad to multiple of 64
      int lp = (off + 63) & ~63;              // <= CAP since off <= CAP
      int i = off + ln;
      if (i < lp) { pkS[r][i].x = 0u; pkS[r][i].y = 0u; }
    }
    if (ln == 0) lenS[r] = off;
  } else {
    // ---- W2T staging (waves 2-4): coalesced read, LDS scatter ----
    for (int e = tid - 128; e < H_DIM * D_OUT; e += 192) {
      int o = e / H_DIM, h = e - o * H_DIM;
      W2T[h * D_OUT + o] = W2[e];
    }
  }
  __syncthreads();

  // ---- Exec: wave j = o-pair, lanes (t, r); 2 LDS ops per entry ----
  float s0 = 0.0f, s1 = 0.0f;
  const int j = tid >> 6;                     // 0..4
  const int lane = tid & 63;
  const int t = lane & 31;
  const int r = lane >> 5;
  const bool ovf = (lenS[0] > CAP) || (lenS[1] > CAP);
  {
    if (!ovf) {
      const int Lpad = (lenS[r] + 63) & ~63;  // per-r trip count (divergent ok)
      const uint2* pp = pkS[r];
      const char* wbase = (const char*)W2T + 8 * j;
#pragma unroll 4
      for (int i = 0; i < Lpad; ++i) {
        uint2 pk = pp[i];                     // b64, 2-distinct broadcast
        float2 w = *(const float2*)(wbase + pk.x);  // b64, 2-distinct
        bool g = (pk.y >> t) & 1u;
        s0 += g ? w.x : 0.0f;                 // identical op to ref (+w / +0)
        s1 += g ? w.y : 0.0f;
      }
    } else {                                  // overflow fallback: gated scan
      const uint32_t* mrow = mb + (size_t)(row0 + r) * H_DIM;
      const uint32_t vbit = 1u << t;
      for (int h = 0; h < H_DIM; ++h) {
        uint32_t mk = mrow[h];
        float2 w = *(const float2*)&W2T[h * D_OUT + 2 * j];
        s0 += (mk & vbit) ? w.x : 0.0f;
        s1 += (mk & vbit) ? w.y : 0.0f;
      }
    }
  }
  __syncthreads();                            // all pk reads complete
  c2s[((r * T_SIM) + t) * D_OUT + 2 * j]     = s0;   // union region write
  c2s[((r * T_SIM) + t) * D_OUT + 2 * j + 1] = s1;
  __syncthreads();

  // ---- Layer-2 IF scan + spike count (exact f32 ref order) ----
  if (tid < 2 * D_OUT) {
    const int rr = tid / D_OUT, o = tid % D_OUT;
    const float bb = b2f[o];
    float v = 0.0f; int cnt = 0;
#pragma unroll
    for (int tt = 0; tt < T_SIM; ++tt) {
      float cur2 = c2s[((rr * T_SIM) + tt) * D_OUT + o] + bb;  // f32 add
      float h2 = v + cur2;                    // f32 add
      bool spk = (h2 >= 1.0f);
      cnt += spk ? 1 : 0;
      v = spk ? 0.0f : h2;
    }
    out[(size_t)(row0 + rr) * D_OUT + o] = (float)cnt;
  }
}

// ---------------------------------------------------------------------------
extern "C" void kernel_launch(void* const* d_in, const int* in_sizes, int n_in,
                              void* d_out, int out_size, void* d_ws, size_t ws_size,
                              hipStream_t stream) {
  const float* x  = (const float*)d_in[0];
  const float* W1 = (const float*)d_in[1];
  const float* b1 = (const float*)d_in[2];
  const float* W2 = (const float*)d_in[3];
  const float* b2 = (const float*)d_in[4];
  float* outp = (float*)d_out;

  float*    xf = (float*)d_ws;                      // N_ELEM f32 (12.85 MB)
  uint32_t* mbuf = (uint32_t*)(xf + N_ELEM);        // B*H u32   (13.1 MB)

  gen_xfixed<<<N_ELEM / 256, 256, 0, stream>>>(x, xf);

  dim3 g1((H_DIM + BN - 1) / BN, B_ROWS / BM);      // 13 x 64 = 832 blocks
  gemm_masks<<<g1, 256, 0, stream>>>(xf, W1, b1, mbuf);

  snn_scan<<<B_ROWS / 2, 320, 0, stream>>>(mbuf, W2, b2, outp);
}